// Round 16
// baseline (422.098 us; speedup 1.0000x reference)
//
#include <hip/hip_runtime.h>

typedef _Float16 f16;
using f16x4 = __attribute__((ext_vector_type(4))) _Float16;
using f16x8 = __attribute__((ext_vector_type(8))) _Float16;
using f32x4 = __attribute__((ext_vector_type(4))) float;

#define HW 65536
#define NBAND 32
#define ROWS 8

// own erf (A&S 7.1.26, |err| <= 1.5e-7); __expf is HW v_exp_f32
static __device__ __forceinline__ float my_erf(float v) {
  float x = fabsf(v);
  float t = 1.f / (1.f + 0.3275911f * x);
  float y = t * (0.254829592f + t * (-0.284496736f + t * (1.421413741f
          + t * (-1.453152027f + t * 1.061405429f))));
  float r = 1.f - y * __expf(-x * x);
  return v < 0.f ? -r : r;
}
static __device__ __forceinline__ float my_gelu(float s) {
  return 0.5f * s * (1.f + my_erf(s * 0.70710678118654752f));
}

__global__ void TRA_Attention_15281493639325_kernel() {}

__global__ void k_signal(float* out, long long n, float val) {
  long long i = (long long)blockIdx.x * blockDim.x + threadIdx.x;
  long long stride = (long long)gridDim.x * blockDim.x;
  for (; i < n; i += stride) out[i] = val;
}

// ---------------------------------------------------------------------------
// K0: one-time weight convert f32 -> f16, plain [256 out][64 in] layout.
// ---------------------------------------------------------------------------
__global__ __launch_bounds__(256) void k0_wconv(
    const float* __restrict__ w_gate, const float* __restrict__ w_qkv,
    f16* __restrict__ W16)
{
  int i = blockIdx.x * 256 + threadIdx.x;     // 0..4095, 4 elems each
  int m = i >> 4, kc = i & 15;
  const float* src = (m < 64) ? (w_gate + m*64 + kc*4)
                              : (w_qkv + (m-64)*64 + kc*4);
  float4 f = *(const float4*)src;
  f16x4 pk = { (f16)f.x, (f16)f.y, (f16)f.z, (f16)f.w };
  *(f16x4*)(W16 + m*64 + kc*4) = pk;
}

// ---------------------------------------------------------------------------
// K1 (MFMA f16, T14 pipeline): fused 1x1 conv, 256 out ch.
// Persistent block = one image row (256 pos) = 4 tiles of 64 pos.
// 4-barrier tile isolation (replay-stability proven round 15 — do not relax).
// ---------------------------------------------------------------------------
__global__ __launch_bounds__(256) void k1_mfma(
    const float* __restrict__ x, const f16* __restrict__ W16,
    f16* __restrict__ A)
{
  __shared__ __align__(16) unsigned char xs[8192];    // xT 64 pos x 128B swz
  __shared__ __align__(16) f16 os[256*64];            // epilogue tile 32KB

  const int tid = threadIdx.x, blk = blockIdx.x;
  const int b = blk >> 8;
  const long long row0 = (long long)(blk & 255) * 256;

  const int wave = tid >> 6, lane = tid & 63;
  const int m0 = (wave >> 1) * 128, n0 = (wave & 1) * 32;
  const int lr = lane & 15, lg = lane >> 4;

  float4 pre[4];
  #pragma unroll
  for (int i = 0; i < 4; ++i) {
    int cid = tid + (i << 8), k = cid >> 4, c = cid & 15;
    pre[i] = *(const float4*)(x + ((long long)b*64 + k)*HW + row0 + c*4);
  }

  for (int t = 0; t < 4; ++t) {
    const long long p0 = row0 + t*64;

    #pragma unroll
    for (int i = 0; i < 4; ++i) {
      int cid = tid + (i << 8), k = cid >> 4, c = cid & 15;
      const float* e = (const float*)&pre[i];
      #pragma unroll
      for (int j = 0; j < 4; ++j) {
        int p = c*4 + j;
        int hp = ((p & 7) ^ ((p >> 3) & 7)) << 4;
        *(f16*)(xs + p*128 + ((2*k) ^ hp)) = (f16)e[j];
      }
    }
    __syncthreads();                       // barrier 1: xs ready

    if (t < 3) {                           // issue next-tile loads EARLY (T14)
      const long long pn = row0 + (t+1)*64;
      #pragma unroll
      for (int i = 0; i < 4; ++i) {
        int cid = tid + (i << 8), k = cid >> 4, c = cid & 15;
        pre[i] = *(const float4*)(x + ((long long)b*64 + k)*HW + pn + c*4);
      }
    }

    f32x4 acc[8][2];
    #pragma unroll
    for (int i = 0; i < 8; ++i)
      #pragma unroll
      for (int j = 0; j < 2; ++j) acc[i][j] = (f32x4){0.f,0.f,0.f,0.f};

    #pragma unroll
    for (int ks = 0; ks < 2; ++ks) {
      f16x8 af[8], bfr[2];
      #pragma unroll
      for (int mi = 0; mi < 8; ++mi) {
        int m = m0 + mi*16 + lr;
        af[mi] = *(const f16x8*)(W16 + m*64 + ks*32 + lg*8);  // L1-hot
      }
      #pragma unroll
      for (int ni = 0; ni < 2; ++ni) {
        int p = n0 + ni*16 + lr;
        int hp = ((p & 7) ^ ((p >> 3) & 7)) << 4;
        bfr[ni] = *(const f16x8*)(xs + p*128 + ((ks*64 + lg*16) ^ hp));
      }
      #pragma unroll
      for (int mi = 0; mi < 8; ++mi)
        #pragma unroll
        for (int ni = 0; ni < 2; ++ni)
          acc[mi][ni] = __builtin_amdgcn_mfma_f32_16x16x32_f16(
              af[mi], bfr[ni], acc[mi][ni], 0, 0, 0);
    }
    __syncthreads();                       // barrier 2: xs reads done

    #pragma unroll
    for (int mi = 0; mi < 8; ++mi)
      #pragma unroll
      for (int ni = 0; ni < 2; ++ni)
        #pragma unroll
        for (int r = 0; r < 4; ++r) {
          int m = m0 + mi*16 + lg*4 + r;
          int p = n0 + ni*16 + lr;
          os[m*64 + (p ^ ((m & 7) << 3))] = (f16)acc[mi][ni][r];
        }
    __syncthreads();                       // barrier 3: os written

    #pragma unroll
    for (int pass = 0; pass < 8; ++pass) {
      int idx = pass*256 + tid;
      int row = idx >> 3, c8 = idx & 7;
      f16x8 v = *(const f16x8*)((const unsigned char*)os + row*128
                                + ((c8 ^ (row & 7)) * 16));
      *(f16x8*)(A + ((long long)b*256 + row)*HW + p0 + c8*8) = v;
    }
    __syncthreads();                       // barrier 4: tile isolated
  }
}

// ---------------------------------------------------------------------------
// K2a (reg-rolling, LDS-free): depthwise 3x3 for gate (+GELU) and v channels.
// ---------------------------------------------------------------------------
__global__ __launch_bounds__(256) void k2a_dw(
    const f16* __restrict__ A, const float* __restrict__ w_gate_dw,
    const float* __restrict__ w_qkv_dw, f16* __restrict__ Vv, f16* __restrict__ GG)
{
  const int tid = threadIdx.x, blk = blockIdx.x;
  const int yband = blk & 3, ch2 = (blk >> 2) & 127, b = blk >> 9;
  const bool isv = ch2 >= 64;
  const int c = isv ? ch2 - 64 : ch2;
  const f16* src = A + ((long long)b*256 + (isv ? 192 + c : c)) * HW;
  const float* wsrc = isv ? (w_qkv_dw + (128 + c)*9) : (w_gate_dw + c*9);
  f16* dst = (isv ? Vv : GG) + ((long long)b*64 + c) * HW;

  float wd[9];
  #pragma unroll
  for (int j = 0; j < 9; ++j) wd[j] = wsrc[j];

  const int xc = tid & 31, ysub = tid >> 5;
  const int lane = tid & 63;
  const int xbase = xc * 8;
  const int y0 = yband * 64 + ysub * 8;

  float rb[3][10];

  auto load_row = [&](int y, float* r) {
    if (y >= 0 && y < 256) {
      uint4 raw = *(const uint4*)(src + y*256 + xbase);
      const f16* e = (const f16*)&raw;
      #pragma unroll
      for (int t = 0; t < 8; ++t) r[1 + t] = (float)e[t];
    } else {
      #pragma unroll
      for (int t = 0; t < 8; ++t) r[1 + t] = 0.f;
    }
    float lf = __shfl(r[8], lane - 1);
    float rf = __shfl(r[1], lane + 1);
    r[0] = (xc == 0)  ? 0.f : lf;
    r[9] = (xc == 31) ? 0.f : rf;
  };

  load_row(y0 - 1, rb[0]);
  load_row(y0,     rb[1]);

  #pragma unroll
  for (int i = 0; i < 8; ++i) {
    load_row(y0 + i + 1, rb[(i + 2) % 3]);
    const float* rm = rb[i % 3];
    const float* r0 = rb[(i + 1) % 3];
    const float* rp = rb[(i + 2) % 3];
    f16x8 st;
    #pragma unroll
    for (int j = 0; j < 8; ++j) {
      float s = wd[0]*rm[j] + wd[1]*rm[j+1] + wd[2]*rm[j+2]
              + wd[3]*r0[j] + wd[4]*r0[j+1] + wd[5]*r0[j+2]
              + wd[6]*rp[j] + wd[7]*rp[j+1] + wd[8]*rp[j+2];
      if (!isv) s = my_gelu(s);
      st[j] = (f16)s;
    }
    *(f16x8*)(dst + (y0 + i)*256 + xbase) = st;
  }
}

// ---------------------------------------------------------------------------
// K2b (MFMA gram, reg-resident rows): dwconv for q,k of one head fused with
// the 16x16 gram via mfma_f32_16x16x32_f16 (identical A/B fragments).
// One wave per (b,h,8-row band). Rows y-1,y,y+1 live in registers (3x8 f16x8);
// LDS is a single 8.4KB transpose slot (stride 264 f16 -> granule step 1 mod 8,
// even spread for b128); x-halos via __shfl, image edges zero-padded in
// selects. grid = nb*8*NBAND.  GRP: [b][h][band][80] = qq[8], kk[8], qk[64].
// ---------------------------------------------------------------------------
__global__ __launch_bounds__(64) void k2b_qk(
    const f16* __restrict__ A, const float* __restrict__ w_qkv_dw,
    float* __restrict__ GRP)
{
  __shared__ __align__(16) f16 slot[16*264];   // 8448 B
  const int lane = threadIdx.x, blk = blockIdx.x;
  const int band = blk & (NBAND-1), h = (blk >> 5) & 7, b = blk >> 8;

  const int c  = lane & 15, g  = lane >> 4;   // compute role
  const int cs = lane >> 2, q4 = lane & 3;    // staging role

  const int wrow = (c < 8) ? (h*8 + c) : (64 + h*8 + (c - 8));
  float wq[9];
  #pragma unroll
  for (int j = 0; j < 9; ++j) wq[j] = w_qkv_dw[wrow*9 + j];

  const f16* sbase = A + ((long long)b*256 +
      (cs < 8 ? 64 + h*8 + cs : 128 + h*8 + (cs - 8))) * HW;

  f16x8 Ra[8], Rb[8], Rc[8];
  f32x4 acc = (f32x4){0.f, 0.f, 0.f, 0.f};

  auto fetch_row = [&](int yy, f16x8* R) {
    uint4 r[8];
    if (yy >= 0 && yy < 256) {
      const f16* p = sbase + yy*256 + q4*64;
      #pragma unroll
      for (int t = 0; t < 8; ++t) r[t] = *(const uint4*)(p + t*8);
    } else {
      #pragma unroll
      for (int t = 0; t < 8; ++t) r[t] = make_uint4(0u,0u,0u,0u);
    }
    __syncthreads();                     // prior slot reads complete
    #pragma unroll
    for (int t = 0; t < 8; ++t)
      *(uint4*)&slot[cs*264 + q4*64 + t*8] = r[t];
    __syncthreads();                     // slot ready
    #pragma unroll
    for (int q = 0; q < 8; ++q)
      R[q] = *(const f16x8*)&slot[c*264 + q*32 + g*8];
  };

  // one row's contribution (taps w[0..2]) into fr[0..7] for chunk q
  auto conv_accum = [&](const f16x8* R, const float* w, float* fr, int q) {
    float v[10];
    #pragma unroll
    for (int t = 0; t < 8; ++t) v[1 + t] = (float)R[q][t];
    float e7p = (q > 0) ? (float)R[q-1][7] : 0.f;
    float e0n = (q < 7) ? (float)R[q+1][0] : 0.f;
    float L1 = __shfl(v[8], lane - 16);          // (c,g-1) chunk q, e7
    float L2 = __shfl(e7p, (lane & 15) + 48);    // (c,3) chunk q-1, e7
    float Q1 = __shfl(v[1], lane + 16);          // (c,g+1) chunk q, e0
    float Q2 = __shfl(e0n, lane & 15);           // (c,0) chunk q+1, e0
    v[0] = (g > 0) ? L1 : ((q > 0) ? L2 : 0.f);
    v[9] = (g < 3) ? Q1 : ((q < 7) ? Q2 : 0.f);
    #pragma unroll
    for (int j = 0; j < 8; ++j)
      fr[j] += w[0]*v[j] + w[1]*v[j+1] + w[2]*v[j+2];
  };

  auto do_row = [&](const f16x8* RM, const f16x8* RC, const f16x8* RP) {
    #pragma unroll
    for (int q = 0; q < 8; ++q) {
      float fr[8] = {0.f,0.f,0.f,0.f,0.f,0.f,0.f,0.f};
      conv_accum(RM, wq + 0, fr, q);
      conv_accum(RC, wq + 3, fr, q);
      conv_accum(RP, wq + 6, fr, q);
      f16x8 frag;
      #pragma unroll
      for (int j = 0; j < 8; ++j) frag[j] = (f16)fr[j];
      acc = __builtin_amdgcn_mfma_f32_16x16x32_f16(frag, frag, acc, 0, 0, 0);
    }
  };

  const int y0 = band * ROWS;
  fetch_row(y0 - 1, Ra);
  fetch_row(y0,     Rb);
  fetch_row(y0 + 1, Rc); do_row(Ra, Rb, Rc);
  fetch_row(y0 + 2, Ra); do_row(Rb, Rc, Ra);
  fetch_row(y0 + 3, Rb); do_row(Rc, Ra, Rb);
  fetch_row(y0 + 4, Rc); do_row(Ra, Rb, Rc);
  fetch_row(y0 + 5, Ra); do_row(Rb, Rc, Ra);
  fetch_row(y0 + 6, Rb); do_row(Rc, Ra, Rb);
  fetch_row(y0 + 7, Rc); do_row(Ra, Rb, Rc);
  fetch_row(y0 + 8, Ra); do_row(Rb, Rc, Ra);

  // D layout: col = lane&15, row = (lane>>4)*4 + reg  -> extract 80 values
  const long long gbase = (long long)((b*8 + h)*NBAND + band) * 80;
  #pragma unroll
  for (int reg = 0; reg < 4; ++reg) {
    int rrow = g*4 + reg;
    float val = acc[reg];
    if (rrow == c) GRP[gbase + c] = val;
    else if (rrow < 8 && c >= 8) GRP[gbase + 16 + rrow*8 + (c-8)] = val;
  }
}

// ---------------------------------------------------------------------------
// K2c: reduce band partials, normalize, temperature, softmax. grid = nb*8
// ---------------------------------------------------------------------------
__global__ __launch_bounds__(64) void k2c_attn(
    const float* __restrict__ GRP, const float* __restrict__ temp,
    float* __restrict__ ATT)
{
  __shared__ float s[80];
  const int tid = threadIdx.x;
  const int h = blockIdx.x & 7, b = blockIdx.x >> 3;
  for (int i = tid; i < 80; i += 64) {
    float v = 0.f;
    for (int band = 0; band < NBAND; ++band)
      v += GRP[(((b*8 + h)*NBAND + band) * 80) + i];
    s[i] = v;
  }
  __syncthreads();
  const int c = tid >> 3, d = tid & 7;
  float nq = fmaxf(sqrtf(s[c]), 1e-12f);
  float nk = fmaxf(sqrtf(s[8 + d]), 1e-12f);
  float logit = s[16 + c*8 + d] / (nq * nk) * temp[h];
  float m = logit;
  #pragma unroll
  for (int off = 4; off; off >>= 1) m = fmaxf(m, __shfl_xor(m, off));
  float e = __expf(logit - m);
  float sum = e;
  #pragma unroll
  for (int off = 4; off; off >>= 1) sum += __shfl_xor(sum, off);
  ATT[((b*8 + h)*8 + c)*8 + d] = e / sum;
}

// ---------------------------------------------------------------------------
// K3 (MFMA proj): g = gelu(gate)*(attn@v) -> f16 LDS tile -> MFMA with
// w_proj (f16) -> f32 out. Block = 256 thr, one image row (256 pos).
// grid = nb*256.
// ---------------------------------------------------------------------------
__global__ __launch_bounds__(256) void k3_out(
    const f16* __restrict__ Vv, const f16* __restrict__ GG,
    const float* __restrict__ ATT, const float* __restrict__ w_proj,
    float* __restrict__ out)
{
  __shared__ __align__(16) unsigned char lds[64*128 + 256*128 + 2048];
  unsigned char* wl = lds;                    // wp f16 [64co][64ch] swz rows
  unsigned char* xs = lds + 64*128;           // g  f16 [256pos][64ch] swz rows
  float* attn_s = (float*)(lds + 64*128 + 256*128);

  const int tid = threadIdx.x;
  const int y = blockIdx.x & 255, b = blockIdx.x >> 8;

  for (int cid = tid; cid < 1024; cid += 256) {
    int m = cid >> 4, kc = cid & 15;
    float4 f = *(const float4*)(w_proj + m*64 + kc*4);
    int hm = ((m & 7) ^ ((m >> 3) & 7)) << 4;
    f16x4 pk = { (f16)f.x, (f16)f.y, (f16)f.z, (f16)f.w };
    *(f16x4*)(wl + m*128 + ((kc*8) ^ hm)) = pk;
  }
  for (int i = tid; i < 512; i += 256) attn_s[i] = ATT[b*512 + i];
  __syncthreads();

  {
    const int pg = tid & 31, hd = tid >> 5;
    const long long base = ((long long)b*64 + hd*8)*HW + (long long)y*256 + pg*8;
    f16x8 vv[8], gg[8];
    #pragma unroll
    for (int d = 0; d < 8; ++d)
      vv[d] = *(const f16x8*)(Vv + base + (long long)d*HW);
    #pragma unroll
    for (int c = 0; c < 8; ++c)
      gg[c] = *(const f16x8*)(GG + base + (long long)c*HW);
    float a[8][8];
    #pragma unroll
    for (int c = 0; c < 8; ++c)
      #pragma unroll
      for (int d = 0; d < 8; ++d) a[c][d] = attn_s[hd*64 + c*8 + d];
    #pragma unroll
    for (int j = 0; j < 8; ++j) {
      int p = pg*8 + j;
      int hp = ((p & 7) ^ ((p >> 3) & 7)) << 4;
      f16x8 st;
      #pragma unroll
      for (int c = 0; c < 8; ++c) {
        float av = 0.f;
        #pragma unroll
        for (int d = 0; d < 8; ++d) av += a[c][d] * (float)vv[d][j];
        st[c] = (f16)((float)gg[c][j] * av);
      }
      *(f16x8*)(xs + p*128 + ((hd*16) ^ hp)) = st;
    }
  }
  __syncthreads();

  const int wave = tid >> 6, lane = tid & 63;
  const int n0 = wave * 64;
  const int lr = lane & 15, lg = lane >> 4;

  f32x4 acc[4][4];
  #pragma unroll
  for (int i = 0; i < 4; ++i)
    #pragma unroll
    for (int j = 0; j < 4; ++j) acc[i][j] = (f32x4){0.f,0.f,0.f,0.f};

  #pragma unroll
  for (int ks = 0; ks < 2; ++ks) {
    f16x8 af[4], bfr[4];
    #pragma unroll
    for (int mi = 0; mi < 4; ++mi) {
      int m = mi*16 + lr;
      int hm = ((m & 7) ^ ((m >> 3) & 7)) << 4;
      af[mi] = *(const f16x8*)(wl + m*128 + ((ks*64 + lg*16) ^ hm));
    }
    #pragma unroll
    for (int ni = 0; ni < 4; ++ni) {
      int p = n0 + ni*16 + lr;
      int hp = ((p & 7) ^ ((p >> 3) & 7)) << 4;
      bfr[ni] = *(const f16x8*)(xs + p*128 + ((ks*64 + lg*16) ^ hp));
    }
    #pragma unroll
    for (int mi = 0; mi < 4; ++mi)
      #pragma unroll
      for (int ni = 0; ni < 4; ++ni)
        acc[mi][ni] = __builtin_amdgcn_mfma_f32_16x16x32_f16(
            af[mi], bfr[ni], acc[mi][ni], 0, 0, 0);
  }

  const long long obase = (long long)b*64*HW + (long long)y*256;
  #pragma unroll
  for (int mi = 0; mi < 4; ++mi)
    #pragma unroll
    for (int ni = 0; ni < 4; ++ni)
      #pragma unroll
      for (int r = 0; r < 4; ++r) {
        int m = mi*16 + lg*4 + r;
        int p = n0 + ni*16 + lr;
        out[obase + (long long)m*HW + p] = acc[mi][ni][r];
      }
}

// ---------------------------------------------------------------------------
extern "C" void kernel_launch(void* const* d_in, const int* in_sizes, int n_in,
                              void* d_out, int out_size, void* d_ws, size_t ws_size,
                              hipStream_t stream)
{
  float* out = (float*)d_out;

  int mp[7] = {-1,-1,-1,-1,-1,-1,-1};
  bool ok = (n_in == 7);
  if (ok) {
    int n4 = 0;
    for (int i = 0; i < 7; ++i) {
      long s = in_sizes[i];
      if      (s == 33554432) mp[0] = i;            // x
      else if (s == 576)      mp[2] = i;            // w_gate_dw
      else if (s == 12288)    mp[3] = i;            // w_qkv
      else if (s == 1728)     mp[4] = i;            // w_qkv_dw
      else if (s == 8)        mp[6] = i;            // temperature
      else if (s == 4096)     { if (n4 == 0) mp[1] = i; else mp[5] = i; ++n4; }
    }
    ok = ok && (n4 == 2);
    for (int i = 0; i < 7; ++i) ok = ok && (mp[i] >= 0);
  }
  if (!ok) { k_signal<<<2048,256,0,stream>>>(out, (long long)out_size, 2000.0f); return; }
  if (out_size != 33554432) { k_signal<<<2048,256,0,stream>>>(out, (long long)out_size, 3000.0f); return; }

  const float* x    = (const float*)d_in[mp[0]];
  const float* wg   = (const float*)d_in[mp[1]];
  const float* wgd  = (const float*)d_in[mp[2]];
  const float* wqkv = (const float*)d_in[mp[3]];
  const float* wqd  = (const float*)d_in[mp[4]];
  const float* wpj  = (const float*)d_in[mp[5]];
  const float* tp   = (const float*)d_in[mp[6]];

  unsigned char* ws = (unsigned char*)d_ws;
  const size_t GRP_SZ   = 8UL*8*NBAND*80*4;            // 655,360
  const size_t FULL     = 402653184UL + GRP_SZ + 16384UL + 32768UL;
  const size_t PERB_GRP = 8UL*NBAND*80*4;              // 81,920
  const size_t PERB     = 50331648UL + PERB_GRP + 2048UL + 32768UL;

  if (ws != nullptr && ws_size >= FULL) {
    f16*   A    = (f16*)ws;
    f16*   Vv   = (f16*)(ws + 268435456UL);
    f16*   GG   = (f16*)(ws + 335544320UL);
    float* GRP  = (float*)(ws + 402653184UL);
    float* ATT  = (float*)(ws + 402653184UL + GRP_SZ);
    f16*   W16  = (f16*)(ws + 402653184UL + GRP_SZ + 16384UL);
    k0_wconv<<<16,   256, 0, stream>>>(wg, wqkv, W16);
    k1_mfma <<<2048, 256, 0, stream>>>(x, W16, A);
    k2a_dw  <<<4096, 256, 0, stream>>>(A, wgd, wqd, Vv, GG);
    k2b_qk  <<<8*8*NBAND, 64, 0, stream>>>(A, wqd, GRP);
    k2c_attn<<<64,   64,  0, stream>>>(GRP, tp, ATT);
    k3_out  <<<2048, 256, 0, stream>>>(Vv, GG, ATT, wpj, out);
  } else if (ws != nullptr && ws_size >= PERB) {
    f16*   A    = (f16*)ws;
    f16*   Vv   = (f16*)(ws + 33554432UL);
    f16*   GG   = (f16*)(ws + 41943040UL);
    float* GRP  = (float*)(ws + 50331648UL);
    float* ATT  = (float*)(ws + 50331648UL + PERB_GRP);
    f16*   W16  = (f16*)(ws + 50331648UL + PERB_GRP + 2048UL);
    k0_wconv<<<16, 256, 0, stream>>>(wg, wqkv, W16);
    for (int b = 0; b < 8; ++b) {
      const float* xb = x + (long long)b*64*HW;
      float* ob = out + (long long)b*64*HW;
      k1_mfma <<<256,  256, 0, stream>>>(xb, W16, A);
      k2a_dw  <<<512,  256, 0, stream>>>(A, wgd, wqd, Vv, GG);
      k2b_qk  <<<8*NBAND, 64, 0, stream>>>(A, wqd, GRP);
      k2c_attn<<<8,    64,  0, stream>>>(GRP, tp, ATT);
      k3_out  <<<256,  256, 0, stream>>>(Vv, GG, ATT, wpj, ob);
    }
  } else {
    k_signal<<<2048,256,0,stream>>>(out, (long long)out_size, 1000.0f);
  }
}

// Round 17
// 270.188 us; speedup vs baseline: 1.5622x; 1.5622x over previous
//
#include <hip/hip_runtime.h>

typedef _Float16 f16;
using f16x4 = __attribute__((ext_vector_type(4))) _Float16;
using f16x8 = __attribute__((ext_vector_type(8))) _Float16;
using f32x4 = __attribute__((ext_vector_type(4))) float;

#define HW 65536
#define NBAND 16
#define ROWS 16
#define RS 320   // k2b ring row stride in f16

// own erf (A&S 7.1.26, |err| <= 1.5e-7); __expf is HW v_exp_f32
static __device__ __forceinline__ float my_erf(float v) {
  float x = fabsf(v);
  float t = 1.f / (1.f + 0.3275911f * x);
  float y = t * (0.254829592f + t * (-0.284496736f + t * (1.421413741f
          + t * (-1.453152027f + t * 1.061405429f))));
  float r = 1.f - y * __expf(-x * x);
  return v < 0.f ? -r : r;
}
static __device__ __forceinline__ float my_gelu(float s) {
  return 0.5f * s * (1.f + my_erf(s * 0.70710678118654752f));
}

__global__ void TRA_Attention_15281493639325_kernel() {}

__global__ void k_signal(float* out, long long n, float val) {
  long long i = (long long)blockIdx.x * blockDim.x + threadIdx.x;
  long long stride = (long long)gridDim.x * blockDim.x;
  for (; i < n; i += stride) out[i] = val;
}

// ---------------------------------------------------------------------------
// K0: one-time weight convert f32 -> f16, plain [256 out][64 in] layout.
// ---------------------------------------------------------------------------
__global__ __launch_bounds__(256) void k0_wconv(
    const float* __restrict__ w_gate, const float* __restrict__ w_qkv,
    f16* __restrict__ W16)
{
  int i = blockIdx.x * 256 + threadIdx.x;     // 0..4095, 4 elems each
  int m = i >> 4, kc = i & 15;
  const float* src = (m < 64) ? (w_gate + m*64 + kc*4)
                              : (w_qkv + (m-64)*64 + kc*4);
  float4 f = *(const float4*)src;
  f16x4 pk = { (f16)f.x, (f16)f.y, (f16)f.z, (f16)f.w };
  *(f16x4*)(W16 + m*64 + kc*4) = pk;
}

// ---------------------------------------------------------------------------
// K1 (MFMA f16, T14 pipeline): fused 1x1 conv, 256 out ch.
// Persistent block = one image row (256 pos) = 4 tiles of 64 pos.
// 4-barrier tile isolation (replay-stability proven round 15 — do not relax).
// ---------------------------------------------------------------------------
__global__ __launch_bounds__(256) void k1_mfma(
    const float* __restrict__ x, const f16* __restrict__ W16,
    f16* __restrict__ A)
{
  __shared__ __align__(16) unsigned char xs[8192];    // xT 64 pos x 128B swz
  __shared__ __align__(16) f16 os[256*64];            // epilogue tile 32KB

  const int tid = threadIdx.x, blk = blockIdx.x;
  const int b = blk >> 8;
  const long long row0 = (long long)(blk & 255) * 256;

  const int wave = tid >> 6, lane = tid & 63;
  const int m0 = (wave >> 1) * 128, n0 = (wave & 1) * 32;
  const int lr = lane & 15, lg = lane >> 4;

  float4 pre[4];
  #pragma unroll
  for (int i = 0; i < 4; ++i) {
    int cid = tid + (i << 8), k = cid >> 4, c = cid & 15;
    pre[i] = *(const float4*)(x + ((long long)b*64 + k)*HW + row0 + c*4);
  }

  for (int t = 0; t < 4; ++t) {
    const long long p0 = row0 + t*64;

    #pragma unroll
    for (int i = 0; i < 4; ++i) {
      int cid = tid + (i << 8), k = cid >> 4, c = cid & 15;
      const float* e = (const float*)&pre[i];
      #pragma unroll
      for (int j = 0; j < 4; ++j) {
        int p = c*4 + j;
        int hp = ((p & 7) ^ ((p >> 3) & 7)) << 4;
        *(f16*)(xs + p*128 + ((2*k) ^ hp)) = (f16)e[j];
      }
    }
    __syncthreads();                       // barrier 1: xs ready

    if (t < 3) {                           // issue next-tile loads EARLY (T14)
      const long long pn = row0 + (t+1)*64;
      #pragma unroll
      for (int i = 0; i < 4; ++i) {
        int cid = tid + (i << 8), k = cid >> 4, c = cid & 15;
        pre[i] = *(const float4*)(x + ((long long)b*64 + k)*HW + pn + c*4);
      }
    }

    f32x4 acc[8][2];
    #pragma unroll
    for (int i = 0; i < 8; ++i)
      #pragma unroll
      for (int j = 0; j < 2; ++j) acc[i][j] = (f32x4){0.f,0.f,0.f,0.f};

    #pragma unroll
    for (int ks = 0; ks < 2; ++ks) {
      f16x8 af[8], bfr[2];
      #pragma unroll
      for (int mi = 0; mi < 8; ++mi) {
        int m = m0 + mi*16 + lr;
        af[mi] = *(const f16x8*)(W16 + m*64 + ks*32 + lg*8);  // L1-hot
      }
      #pragma unroll
      for (int ni = 0; ni < 2; ++ni) {
        int p = n0 + ni*16 + lr;
        int hp = ((p & 7) ^ ((p >> 3) & 7)) << 4;
        bfr[ni] = *(const f16x8*)(xs + p*128 + ((ks*64 + lg*16) ^ hp));
      }
      #pragma unroll
      for (int mi = 0; mi < 8; ++mi)
        #pragma unroll
        for (int ni = 0; ni < 2; ++ni)
          acc[mi][ni] = __builtin_amdgcn_mfma_f32_16x16x32_f16(
              af[mi], bfr[ni], acc[mi][ni], 0, 0, 0);
    }
    __syncthreads();                       // barrier 2: xs reads done

    #pragma unroll
    for (int mi = 0; mi < 8; ++mi)
      #pragma unroll
      for (int ni = 0; ni < 2; ++ni)
        #pragma unroll
        for (int r = 0; r < 4; ++r) {
          int m = m0 + mi*16 + lg*4 + r;
          int p = n0 + ni*16 + lr;
          os[m*64 + (p ^ ((m & 7) << 3))] = (f16)acc[mi][ni][r];
        }
    __syncthreads();                       // barrier 3: os written

    #pragma unroll
    for (int pass = 0; pass < 8; ++pass) {
      int idx = pass*256 + tid;
      int row = idx >> 3, c8 = idx & 7;
      f16x8 v = *(const f16x8*)((const unsigned char*)os + row*128
                                + ((c8 ^ (row & 7)) * 16));
      *(f16x8*)(A + ((long long)b*256 + row)*HW + p0 + c8*8) = v;
    }
    __syncthreads();                       // barrier 4: tile isolated
  }
}

// ---------------------------------------------------------------------------
// K2a (reg-rolling, LDS-free): depthwise 3x3 for gate (+GELU) and v channels.
// ---------------------------------------------------------------------------
__global__ __launch_bounds__(256) void k2a_dw(
    const f16* __restrict__ A, const float* __restrict__ w_gate_dw,
    const float* __restrict__ w_qkv_dw, f16* __restrict__ Vv, f16* __restrict__ GG)
{
  const int tid = threadIdx.x, blk = blockIdx.x;
  const int yband = blk & 3, ch2 = (blk >> 2) & 127, b = blk >> 9;
  const bool isv = ch2 >= 64;
  const int c = isv ? ch2 - 64 : ch2;
  const f16* src = A + ((long long)b*256 + (isv ? 192 + c : c)) * HW;
  const float* wsrc = isv ? (w_qkv_dw + (128 + c)*9) : (w_gate_dw + c*9);
  f16* dst = (isv ? Vv : GG) + ((long long)b*64 + c) * HW;

  float wd[9];
  #pragma unroll
  for (int j = 0; j < 9; ++j) wd[j] = wsrc[j];

  const int xc = tid & 31, ysub = tid >> 5;
  const int lane = tid & 63;
  const int xbase = xc * 8;
  const int y0 = yband * 64 + ysub * 8;

  float rb[3][10];

  auto load_row = [&](int y, float* r) {
    if (y >= 0 && y < 256) {
      uint4 raw = *(const uint4*)(src + y*256 + xbase);
      const f16* e = (const f16*)&raw;
      #pragma unroll
      for (int t = 0; t < 8; ++t) r[1 + t] = (float)e[t];
    } else {
      #pragma unroll
      for (int t = 0; t < 8; ++t) r[1 + t] = 0.f;
    }
    float lf = __shfl(r[8], lane - 1);
    float rf = __shfl(r[1], lane + 1);
    r[0] = (xc == 0)  ? 0.f : lf;
    r[9] = (xc == 31) ? 0.f : rf;
  };

  load_row(y0 - 1, rb[0]);
  load_row(y0,     rb[1]);

  #pragma unroll
  for (int i = 0; i < 8; ++i) {
    load_row(y0 + i + 1, rb[(i + 2) % 3]);
    const float* rm = rb[i % 3];
    const float* r0 = rb[(i + 1) % 3];
    const float* rp = rb[(i + 2) % 3];
    f16x8 st;
    #pragma unroll
    for (int j = 0; j < 8; ++j) {
      float s = wd[0]*rm[j] + wd[1]*rm[j+1] + wd[2]*rm[j+2]
              + wd[3]*r0[j] + wd[4]*r0[j+1] + wd[5]*r0[j+2]
              + wd[6]*rp[j] + wd[7]*rp[j+1] + wd[8]*rp[j+2];
      if (!isv) s = my_gelu(s);
      st[j] = (f16)s;
    }
    *(f16x8*)(dst + (y0 + i)*256 + xbase) = st;
  }
}

// ---------------------------------------------------------------------------
// K2b (MFMA gram, ring + wide reads): dwconv for q,k of one head fused with
// the 16x16 gram via mfma_f32_16x16x32_f16 (identical A/B fragments).
// Ring staging/prefetch/barriers = round-15 (proven stable).  Compute reads =
// 24x ds_read_b128 per row (8 f16x8 per slot) + round-16's verified __shfl
// x-halo logic — replaces 240 scalar conflicted ds_read_u16 per row.
// 1 wave per (b,h,16-row band).  GRP: [b][h][band][80] = qq[8], kk[8], qk[64].
// ---------------------------------------------------------------------------
__device__ __forceinline__ int ridx(int c, int slot, int i) {
  return ((((c << 2) | slot) * RS) + i) ^ ((c & 7) << 3);
}

__global__ __launch_bounds__(64) void k2b_qk(
    const f16* __restrict__ A, const float* __restrict__ w_qkv_dw,
    float* __restrict__ GRP)
{
  __shared__ __align__(16) f16 ring[16*4*RS];
  const int lane = threadIdx.x, blk = blockIdx.x;
  const int band = blk & (NBAND-1), h = (blk >> 4) & 7, b = blk >> 7;

  const int c  = lane & 15, g  = lane >> 4;   // compute role
  const int cs = lane >> 2, q4 = lane & 3;    // staging role

  const int wrow = (c < 8) ? (h*8 + c) : (64 + h*8 + (c - 8));
  float wq[9];
  #pragma unroll
  for (int j = 0; j < 9; ++j) wq[j] = w_qkv_dw[wrow*9 + j];

  const f16* sbase = A + ((long long)b*256 +
      (cs < 8 ? 64 + h*8 + cs : 128 + h*8 + (cs - 8))) * HW;

  auto load_row = [&](int yy, uint4* r) {
    if (yy >= 0 && yy < 256) {
      const f16* p = sbase + yy*256 + q4*64;
      #pragma unroll
      for (int t = 0; t < 8; ++t) r[t] = *(const uint4*)(p + t*8);
    } else {
      #pragma unroll
      for (int t = 0; t < 8; ++t) r[t] = make_uint4(0u,0u,0u,0u);
    }
  };
  auto write_row = [&](int slot, const uint4* r) {
    #pragma unroll
    for (int t = 0; t < 8; ++t)
      *(uint4*)&ring[ridx(cs, slot, 8 + q4*64 + t*8)] = r[t];
  };

  // one row's contribution (taps w[0..2]) into fr[0..7] for chunk q
  // (verified bit-exact in round 16)
  auto conv_accum = [&](const f16x8* R, const float* w, float* fr, int q) {
    float v[10];
    #pragma unroll
    for (int t = 0; t < 8; ++t) v[1 + t] = (float)R[q][t];
    float e7p = (q > 0) ? (float)R[q-1][7] : 0.f;
    float e0n = (q < 7) ? (float)R[q+1][0] : 0.f;
    float L1 = __shfl(v[8], lane - 16);          // (c,g-1) chunk q, e7
    float L2 = __shfl(e7p, (lane & 15) + 48);    // (c,3) chunk q-1, e7
    float Q1 = __shfl(v[1], lane + 16);          // (c,g+1) chunk q, e0
    float Q2 = __shfl(e0n, lane & 15);           // (c,0) chunk q+1, e0
    v[0] = (g > 0) ? L1 : ((q > 0) ? L2 : 0.f);
    v[9] = (g < 3) ? Q1 : ((q < 7) ? Q2 : 0.f);
    #pragma unroll
    for (int j = 0; j < 8; ++j)
      fr[j] += w[0]*v[j] + w[1]*v[j+1] + w[2]*v[j+2];
  };

  f32x4 acc = (f32x4){0.f, 0.f, 0.f, 0.f};

  const int y0 = band * ROWS;
  {
    uint4 r[8];
    load_row(y0-1, r); write_row((y0+3)&3, r);
    load_row(y0,   r); write_row((y0+4)&3, r);
    load_row(y0+1, r); write_row((y0+5)&3, r);
  }
  __syncthreads();

  for (int y = y0; y < y0 + ROWS; ++y) {
    uint4 r[8];
    const bool pf = (y + 2 <= y0 + ROWS);
    if (pf) load_row(y + 2, r);              // issue early (T14)

    const int s0 = (y+3)&3, s1 = (y+4)&3, s2 = (y+5)&3;
    f16x8 Rm[8], Rc[8], Rp[8];
    #pragma unroll
    for (int q = 0; q < 8; ++q) {
      Rm[q] = *(const f16x8*)&ring[ridx(c, s0, 8 + q*32 + g*8)];
      Rc[q] = *(const f16x8*)&ring[ridx(c, s1, 8 + q*32 + g*8)];
      Rp[q] = *(const f16x8*)&ring[ridx(c, s2, 8 + q*32 + g*8)];
    }

    #pragma unroll
    for (int q = 0; q < 8; ++q) {
      float fr[8] = {0.f,0.f,0.f,0.f,0.f,0.f,0.f,0.f};
      conv_accum(Rm, wq + 0, fr, q);
      conv_accum(Rc, wq + 3, fr, q);
      conv_accum(Rp, wq + 6, fr, q);
      f16x8 frag;
      #pragma unroll
      for (int j = 0; j < 8; ++j) frag[j] = (f16)fr[j];
      acc = __builtin_amdgcn_mfma_f32_16x16x32_f16(frag, frag, acc, 0, 0, 0);
    }

    if (pf) write_row((y+6)&3, r);           // write late, after reads
    __syncthreads();
  }

  // D layout: col = lane&15, row = (lane>>4)*4 + reg  -> extract 80 values
  const long long gbase = (long long)((b*8 + h)*NBAND + band) * 80;
  #pragma unroll
  for (int reg = 0; reg < 4; ++reg) {
    int rrow = g*4 + reg;
    float val = acc[reg];
    if (rrow == c) GRP[gbase + c] = val;
    else if (rrow < 8 && c >= 8) GRP[gbase + 16 + rrow*8 + (c-8)] = val;
  }
}

// ---------------------------------------------------------------------------
// K2c: reduce band partials, normalize, temperature, softmax. grid = nb*8
// ---------------------------------------------------------------------------
__global__ __launch_bounds__(64) void k2c_attn(
    const float* __restrict__ GRP, const float* __restrict__ temp,
    float* __restrict__ ATT)
{
  __shared__ float s[80];
  const int tid = threadIdx.x;
  const int h = blockIdx.x & 7, b = blockIdx.x >> 3;
  for (int i = tid; i < 80; i += 64) {
    float v = 0.f;
    for (int band = 0; band < NBAND; ++band)
      v += GRP[(((b*8 + h)*NBAND + band) * 80) + i];
    s[i] = v;
  }
  __syncthreads();
  const int c = tid >> 3, d = tid & 7;
  float nq = fmaxf(sqrtf(s[c]), 1e-12f);
  float nk = fmaxf(sqrtf(s[8 + d]), 1e-12f);
  float logit = s[16 + c*8 + d] / (nq * nk) * temp[h];
  float m = logit;
  #pragma unroll
  for (int off = 4; off; off >>= 1) m = fmaxf(m, __shfl_xor(m, off));
  float e = __expf(logit - m);
  float sum = e;
  #pragma unroll
  for (int off = 4; off; off >>= 1) sum += __shfl_xor(sum, off);
  ATT[((b*8 + h)*8 + c)*8 + d] = e / sum;
}

// ---------------------------------------------------------------------------
// K3 (MFMA proj): g = gelu(gate)*(attn@v) -> f16 LDS tile -> MFMA with
// w_proj (f16) -> f32 out. Block = 256 thr, one image row (256 pos).
// grid = nb*256.
// ---------------------------------------------------------------------------
__global__ __launch_bounds__(256) void k3_out(
    const f16* __restrict__ Vv, const f16* __restrict__ GG,
    const float* __restrict__ ATT, const float* __restrict__ w_proj,
    float* __restrict__ out)
{
  __shared__ __align__(16) unsigned char lds[64*128 + 256*128 + 2048];
  unsigned char* wl = lds;                    // wp f16 [64co][64ch] swz rows
  unsigned char* xs = lds + 64*128;           // g  f16 [256pos][64ch] swz rows
  float* attn_s = (float*)(lds + 64*128 + 256*128);

  const int tid = threadIdx.x;
  const int y = blockIdx.x & 255, b = blockIdx.x >> 8;

  for (int cid = tid; cid < 1024; cid += 256) {
    int m = cid >> 4, kc = cid & 15;
    float4 f = *(const float4*)(w_proj + m*64 + kc*4);
    int hm = ((m & 7) ^ ((m >> 3) & 7)) << 4;
    f16x4 pk = { (f16)f.x, (f16)f.y, (f16)f.z, (f16)f.w };
    *(f16x4*)(wl + m*128 + ((kc*8) ^ hm)) = pk;
  }
  for (int i = tid; i < 512; i += 256) attn_s[i] = ATT[b*512 + i];
  __syncthreads();

  {
    const int pg = tid & 31, hd = tid >> 5;
    const long long base = ((long long)b*64 + hd*8)*HW + (long long)y*256 + pg*8;
    f16x8 vv[8], gg[8];
    #pragma unroll
    for (int d = 0; d < 8; ++d)
      vv[d] = *(const f16x8*)(Vv + base + (long long)d*HW);
    #pragma unroll
    for (int c = 0; c < 8; ++c)
      gg[c] = *(const f16x8*)(GG + base + (long long)c*HW);
    float a[8][8];
    #pragma unroll
    for (int c = 0; c < 8; ++c)
      #pragma unroll
      for (int d = 0; d < 8; ++d) a[c][d] = attn_s[hd*64 + c*8 + d];
    #pragma unroll
    for (int j = 0; j < 8; ++j) {
      int p = pg*8 + j;
      int hp = ((p & 7) ^ ((p >> 3) & 7)) << 4;
      f16x8 st;
      #pragma unroll
      for (int c = 0; c < 8; ++c) {
        float av = 0.f;
        #pragma unroll
        for (int d = 0; d < 8; ++d) av += a[c][d] * (float)vv[d][j];
        st[c] = (f16)((float)gg[c][j] * av);
      }
      *(f16x8*)(xs + p*128 + ((hd*16) ^ hp)) = st;
    }
  }
  __syncthreads();

  const int wave = tid >> 6, lane = tid & 63;
  const int n0 = wave * 64;
  const int lr = lane & 15, lg = lane >> 4;

  f32x4 acc[4][4];
  #pragma unroll
  for (int i = 0; i < 4; ++i)
    #pragma unroll
    for (int j = 0; j < 4; ++j) acc[i][j] = (f32x4){0.f,0.f,0.f,0.f};

  #pragma unroll
  for (int ks = 0; ks < 2; ++ks) {
    f16x8 af[4], bfr[4];
    #pragma unroll
    for (int mi = 0; mi < 4; ++mi) {
      int m = mi*16 + lr;
      int hm = ((m & 7) ^ ((m >> 3) & 7)) << 4;
      af[mi] = *(const f16x8*)(wl + m*128 + ((ks*64 + lg*16) ^ hm));
    }
    #pragma unroll
    for (int ni = 0; ni < 4; ++ni) {
      int p = n0 + ni*16 + lr;
      int hp = ((p & 7) ^ ((p >> 3) & 7)) << 4;
      bfr[ni] = *(const f16x8*)(xs + p*128 + ((ks*64 + lg*16) ^ hp));
    }
    #pragma unroll
    for (int mi = 0; mi < 4; ++mi)
      #pragma unroll
      for (int ni = 0; ni < 4; ++ni)
        acc[mi][ni] = __builtin_amdgcn_mfma_f32_16x16x32_f16(
            af[mi], bfr[ni], acc[mi][ni], 0, 0, 0);
  }

  const long long obase = (long long)b*64*HW + (long long)y*256;
  #pragma unroll
  for (int mi = 0; mi < 4; ++mi)
    #pragma unroll
    for (int ni = 0; ni < 4; ++ni)
      #pragma unroll
      for (int r = 0; r < 4; ++r) {
        int m = mi*16 + lg*4 + r;
        int p = n0 + ni*16 + lr;
        out[obase + (long long)m*HW + p] = acc[mi][ni][r];
      }
}

// ---------------------------------------------------------------------------
extern "C" void kernel_launch(void* const* d_in, const int* in_sizes, int n_in,
                              void* d_out, int out_size, void* d_ws, size_t ws_size,
                              hipStream_t stream)
{
  float* out = (float*)d_out;

  int mp[7] = {-1,-1,-1,-1,-1,-1,-1};
  bool ok = (n_in == 7);
  if (ok) {
    int n4 = 0;
    for (int i = 0; i < 7; ++i) {
      long s = in_sizes[i];
      if      (s == 33554432) mp[0] = i;            // x
      else if (s == 576)      mp[2] = i;            // w_gate_dw
      else if (s == 12288)    mp[3] = i;            // w_qkv
      else if (s == 1728)     mp[4] = i;            // w_qkv_dw
      else if (s == 8)        mp[6] = i;            // temperature
      else if (s == 4096)     { if (n4 == 0) mp[1] = i; else mp[5] = i; ++n4; }
    }
    ok = ok && (n4 == 2);
    for (int i = 0; i < 7; ++i) ok = ok && (mp[i] >= 0);
  }
  if (!ok) { k_signal<<<2048,256,0,stream>>>(out, (long long)out_size, 2000.0f); return; }
  if (out_size != 33554432) { k_signal<<<2048,256,0,stream>>>(out, (long long)out_size, 3000.0f); return; }

  const float* x    = (const float*)d_in[mp[0]];
  const float* wg   = (const float*)d_in[mp[1]];
  const float* wgd  = (const float*)d_in[mp[2]];
  const float* wqkv = (const float*)d_in[mp[3]];
  const float* wqd  = (const float*)d_in[mp[4]];
  const float* wpj  = (const float*)d_in[mp[5]];
  const float* tp   = (const float*)d_in[mp[6]];

  unsigned char* ws = (unsigned char*)d_ws;
  const size_t GRP_SZ   = 8UL*8*NBAND*80*4;            // 327,680
  const size_t FULL     = 402653184UL + GRP_SZ + 16384UL + 32768UL;
  const size_t PERB_GRP = 8UL*NBAND*80*4;              // 40,960
  const size_t PERB     = 50331648UL + PERB_GRP + 2048UL + 32768UL;

  if (ws != nullptr && ws_size >= FULL) {
    f16*   A    = (f16*)ws;
    f16*   Vv   = (f16*)(ws + 268435456UL);
    f16*   GG   = (f16*)(ws + 335544320UL);
    float* GRP  = (float*)(ws + 402653184UL);
    float* ATT  = (float*)(ws + 402653184UL + GRP_SZ);
    f16*   W16  = (f16*)(ws + 402653184UL + GRP_SZ + 16384UL);
    k0_wconv<<<16,   256, 0, stream>>>(wg, wqkv, W16);
    k1_mfma <<<2048, 256, 0, stream>>>(x, W16, A);
    k2a_dw  <<<4096, 256, 0, stream>>>(A, wgd, wqd, Vv, GG);
    k2b_qk  <<<8*8*NBAND, 64, 0, stream>>>(A, wqd, GRP);
    k2c_attn<<<64,   64,  0, stream>>>(GRP, tp, ATT);
    k3_out  <<<2048, 256, 0, stream>>>(Vv, GG, ATT, wpj, out);
  } else if (ws != nullptr && ws_size >= PERB) {
    f16*   A    = (f16*)ws;
    f16*   Vv   = (f16*)(ws + 33554432UL);
    f16*   GG   = (f16*)(ws + 41943040UL);
    float* GRP  = (float*)(ws + 50331648UL);
    float* ATT  = (float*)(ws + 50331648UL + PERB_GRP);
    f16*   W16  = (f16*)(ws + 50331648UL + PERB_GRP + 2048UL);
    k0_wconv<<<16, 256, 0, stream>>>(wg, wqkv, W16);
    for (int b = 0; b < 8; ++b) {
      const float* xb = x + (long long)b*64*HW;
      float* ob = out + (long long)b*64*HW;
      k1_mfma <<<256,  256, 0, stream>>>(xb, W16, A);
      k2a_dw  <<<512,  256, 0, stream>>>(A, wgd, wqd, Vv, GG);
      k2b_qk  <<<8*NBAND, 64, 0, stream>>>(A, wqd, GRP);
      k2c_attn<<<8,    64,  0, stream>>>(GRP, tp, ATT);
      k3_out  <<<256,  256, 0, stream>>>(Vv, GG, ATT, wpj, ob);
    }
  } else {
    k_signal<<<2048,256,0,stream>>>(out, (long long)out_size, 1000.0f);
  }
}